// Round 4
// baseline (113.606 us; speedup 1.0000x reference)
//
#include <hip/hip_runtime.h>
#include <hip/hip_bf16.h>

// out[i][j] = (x@beta)[i][j] - 0.1*y[i][j]*||beta[:,j]||_1
//             + (4096*rowsum(W2)[j] + bias2[j] + bias_lin[j])
// M=4096, K=2048, N=1024. adv==1 always.
//
// Pipeline: memset(braw) -> pre_kernel (x->bf16; beta->bf16 transposed + L1;
// W2 rowsums) -> gemm_kernel (pure bf16, global_load_lds, 3-buf counted vmcnt,
// XOR-swizzled LDS, fused epilogue).

typedef float    f32x4  __attribute__((ext_vector_type(4)));
typedef unsigned u32x2  __attribute__((ext_vector_type(2)));
typedef unsigned u32x4  __attribute__((ext_vector_type(4)));
typedef short    bf16x8 __attribute__((ext_vector_type(8)));
typedef short    s16x4  __attribute__((ext_vector_type(4)));

constexpr int M = 4096;
constexpr int N = 1024;
constexpr int K = 2048;
constexpr int NHID = 4096;

__device__ __forceinline__ unsigned pkbf(float a, float b) {
    __hip_bfloat162 h = __float22bfloat162_rn(make_float2(a, b));
    unsigned u; __builtin_memcpy(&u, &h, 4); return u;
}

__device__ __forceinline__ void gll16(const void* g, void* l) {
    __builtin_amdgcn_global_load_lds(
        (const __attribute__((address_space(1))) void*)g,
        (__attribute__((address_space(3))) void*)l, 16, 0, 0);
}

// =================== pre: cvt x, cvt+transpose beta (+L1), W2 rowsums =======
// grid 1024: [0,256) x->bf16 ; [256,768) beta tiles 64x64 ; [768,1024) W2 rows
__global__ void __launch_bounds__(256) pre_kernel(
    const float* __restrict__ x, const float* __restrict__ beta,
    const float* __restrict__ W2,
    short* __restrict__ xb, short* __restrict__ bt,
    float* __restrict__ braw, float* __restrict__ wsum) {
    __shared__ float tls[64 * 68];
    const int bx = blockIdx.x, tid = threadIdx.x;
    if (bx < 256) {
        const f32x4* x4 = (const f32x4*)x;
        u32x2* o2 = (u32x2*)xb;
        const int base = bx * 256 + tid;
        #pragma unroll
        for (int it = 0; it < 32; ++it) {
            f32x4 v = x4[it * 65536 + base];
            u32x2 p = { pkbf(v[0], v[1]), pkbf(v[2], v[3]) };
            o2[it * 65536 + base] = p;
        }
    } else if (bx < 768) {
        const int tile = bx - 256, tk = tile & 31, tn = tile >> 5;
        {   // phase 1: load 64x64 fp32 tile of beta[k][n] into LDS
            const int r = tid >> 2, c0 = (tid & 3) * 16;
            const float* src = beta + (size_t)(tk * 64 + r) * N + tn * 64 + c0;
            #pragma unroll
            for (int j = 0; j < 4; ++j)
                *(f32x4*)&tls[r * 68 + c0 + j * 4] = *(const f32x4*)(src + j * 4);
        }
        __syncthreads();
        {   // phase 2: write bt[n][k] bf16 + accumulate column L1
            const int n = tid >> 2, k0 = (tid & 3) * 16;
            float s = 0.f;
            unsigned pk[8];
            #pragma unroll
            for (int j = 0; j < 8; ++j) {
                float a = tls[(k0 + 2 * j) * 68 + n];
                float b = tls[(k0 + 2 * j + 1) * 68 + n];
                s += fabsf(a) + fabsf(b);
                pk[j] = pkbf(a, b);
            }
            atomicAdd(&braw[tn * 64 + n], s);
            u32x4* dst = (u32x4*)(bt + (size_t)(tn * 64 + n) * K + tk * 64 + k0);
            u32x4 p0 = { pk[0], pk[1], pk[2], pk[3] };
            u32x4 p1 = { pk[4], pk[5], pk[6], pk[7] };
            dst[0] = p0; dst[1] = p1;
        }
    } else {
        const int b = bx - 768;
        const int wv = tid >> 6, lane = tid & 63;
        const int row = b * 4 + wv;
        const f32x4* w4 = (const f32x4*)(W2 + (size_t)row * NHID);
        float acc = 0.f;
        #pragma unroll
        for (int i = 0; i < 16; ++i) {
            f32x4 v = w4[i * 64 + lane];
            acc += v[0] + v[1] + v[2] + v[3];
        }
        #pragma unroll
        for (int off = 32; off; off >>= 1) acc += __shfl_down(acc, off);
        if (lane == 0) wsum[row] = acc;
    }
}

// =================== main GEMM: bf16, global_load_lds, 3-buf vmcnt(6) =======
// BM=128 x BN=64, BK=64, 4 waves (2m x 2n), wave tile 64x32 (4x2 frags, 2 kk).
// Grid 512 -> 2 blocks/CU. LDS 72KB (3 buffers). One barrier per K-step.
// XOR swizzle: LDS slot (row, c) holds global chunk c^(row&7); reads XOR back.
constexpr int BM = 128, BN = 64, BK = 64;
constexpr int NT  = K / BK;          // 32
constexpr int ASZ = BM * BK;         // 8192 shorts (16KB)
constexpr int BSZ = BN * BK;         // 4096 shorts (8KB)

__global__ void __launch_bounds__(256, 2) gemm_kernel(
    const short* __restrict__ xb, const short* __restrict__ bt,
    const float* __restrict__ y,
    const float* __restrict__ braw, const float* __restrict__ wsum,
    const float* __restrict__ bias_lin, const float* __restrict__ bias2,
    float* __restrict__ out) {
    __shared__ __align__(16) short Al[3 * ASZ];
    __shared__ __align__(16) short Bl[3 * BSZ];

    const int tid = threadIdx.x, lane = tid & 63, w = tid >> 6;
    const int wm = w >> 1, wn = w & 1;
    // XCD swizzle: xcd c gets 16mb x 4nb contiguous region (512 = 8 x 64)
    const int c = blockIdx.x & 7, local = blockIdx.x >> 3;
    const int mb = ((c & 1) << 4) + (local >> 2);
    const int nb = ((c >> 1) << 2) + (local & 3);
    const int brow = mb * BM, bcol = nb * BN;

    // staging: per-lane pre-swizzled global source, linear LDS dest
    const int srow = lane >> 3;                 // 0..7 within 8-row stripe
    const int schk = (lane & 7) ^ srow;         // fetch chunk for slot (srow, lane&7)
    const short* asrc = xb + (size_t)(brow + w * 32 + srow) * K + schk * 8;
    const short* bsrc = bt + (size_t)(bcol + w * 16 + srow) * K + schk * 8;
    short* Abase = &Al[w * 2048];
    short* Bbase = &Bl[w * 1024];

    f32x4 acc[4][2];
    #pragma unroll
    for (int m = 0; m < 4; ++m)
        #pragma unroll
        for (int n = 0; n < 2; ++n) acc[m][n] = (f32x4)0.f;

    auto STAGE = [&](int buf, int t) {
        const short* a = asrc + t * BK;
        #pragma unroll
        for (int i = 0; i < 4; ++i)
            gll16(a + (size_t)i * 8 * K, Abase + buf * ASZ + i * 512);
        const short* b = bsrc + t * BK;
        #pragma unroll
        for (int i = 0; i < 2; ++i)
            gll16(b + (size_t)i * 8 * K, Bbase + buf * BSZ + i * 512);
    };

    // fragment LDS offsets (shorts), with XOR-unswizzle on the chunk index
    const int r = lane & 15, q = lane >> 4;
    int aoff[4][2], boff[2][2];
    #pragma unroll
    for (int m = 0; m < 4; ++m)
        #pragma unroll
        for (int kk = 0; kk < 2; ++kk) {
            int row = wm * 64 + m * 16 + r;
            int ch = (kk * 4 + q) ^ (r & 7);
            aoff[m][kk] = row * 64 + ch * 8;
        }
    #pragma unroll
    for (int n = 0; n < 2; ++n)
        #pragma unroll
        for (int kk = 0; kk < 2; ++kk) {
            int row = wn * 32 + n * 16 + r;
            int ch = (kk * 4 + q) ^ (r & 7);
            boff[n][kk] = row * 64 + ch * 8;
        }

    auto COMPUTE = [&](int buf) {
        const short* A = &Al[buf * ASZ];
        const short* B = &Bl[buf * BSZ];
        #pragma unroll
        for (int kk = 0; kk < 2; ++kk) {
            bf16x8 af[4], bfr[2];
            #pragma unroll
            for (int m = 0; m < 4; ++m) af[m] = *(const bf16x8*)&A[aoff[m][kk]];
            #pragma unroll
            for (int n = 0; n < 2; ++n) bfr[n] = *(const bf16x8*)&B[boff[n][kk]];
            #pragma unroll
            for (int m = 0; m < 4; ++m)
                #pragma unroll
                for (int n = 0; n < 2; ++n)
                    acc[m][n] = __builtin_amdgcn_mfma_f32_16x16x32_bf16(
                        af[m], bfr[n], acc[m][n], 0, 0, 0);
        }
    };

    STAGE(0, 0);
    STAGE(1, 1);
    for (int t = 0; t < NT; ++t) {
        if (t < NT - 1) { asm volatile("s_waitcnt vmcnt(6)" ::: "memory"); }
        else            { asm volatile("s_waitcnt vmcnt(0)" ::: "memory"); }
        __builtin_amdgcn_s_barrier();
        __builtin_amdgcn_sched_barrier(0);
        if (t + 2 < NT) STAGE((t + 2) % 3, t + 2);
        COMPUTE(t % 3);
    }

    // epilogue: out = acc + cterm[col] - 0.1*braw[col]*y
    #pragma unroll
    for (int n = 0; n < 2; ++n) {
        const int gc = bcol + wn * 32 + n * 16 + r;
        const float be = 0.1f * braw[gc];
        const float ct = bias_lin[gc] + bias2[gc] + (float)NHID * wsum[gc];
        #pragma unroll
        for (int m = 0; m < 4; ++m) {
            const int gr0 = brow + wm * 64 + m * 16 + q * 4;
            f32x4 v = acc[m][n];
            #pragma unroll
            for (int rr = 0; rr < 4; ++rr) {
                size_t idx = (size_t)(gr0 + rr) * N + gc;
                out[idx] = v[rr] + ct - be * y[idx];
            }
        }
    }
}

// =================== fallback path (round-3, used only if ws too small) =====
__global__ void prep3_kernel(const float* __restrict__ W2,
                             const float* __restrict__ bias_lin,
                             const float* __restrict__ bias2,
                             float* __restrict__ cterm) {
    int wv = threadIdx.x >> 6, lane = threadIdx.x & 63;
    int row = blockIdx.x * 4 + wv;
    const f32x4* w4 = (const f32x4*)(W2 + (size_t)row * NHID);
    float acc = 0.f;
    #pragma unroll
    for (int i = 0; i < 16; ++i) {
        f32x4 v = w4[i * 64 + lane];
        acc += v[0] + v[1] + v[2] + v[3];
    }
    #pragma unroll
    for (int off = 32; off; off >>= 1) acc += __shfl_down(acc, off);
    if (lane == 0)
        cterm[row] = bias_lin[row] + bias2[row] + (float)NHID * acc;
}

__global__ void __launch_bounds__(256, 4) gemm3_kernel(
    const float* __restrict__ x, const float* __restrict__ beta,
    const float* __restrict__ y, const float* __restrict__ cterm,
    float* __restrict__ out) {
    constexpr int LDA3 = 40, LDB3 = 40;
    __shared__ __align__(16) short Al[2][64 * LDA3];
    __shared__ __align__(16) short Bl[2][64 * LDB3];
    __shared__ float scr[256];

    const int tid = threadIdx.x;
    const int cc = blockIdx.x & 7, local = blockIdx.x >> 3;
    const int mb = ((cc >> 2) << 5) + (local >> 2);
    const int nb = ((cc & 3) << 2) + (local & 3);
    const int brow = mb * 64, bcol = nb * 64;
    const int lane = tid & 63, w = tid >> 6;
    const int wm = w >> 1, wn = w & 1;

    const int arow = tid >> 3, ak4 = (tid & 7) * 4;
    const float* apb = x + (size_t)(brow + arow) * K + ak4;
    const int awr = arow * LDA3 + ak4;
    const int bn_ = tid & 63, bkc = (tid >> 6) * 8;
    const float* bpb = beta + (size_t)bkc * N + bcol + bn_;
    const int bwr = bn_ * LDB3 + bkc;

    f32x4 acc[2][2];
    #pragma unroll
    for (int m = 0; m < 2; ++m)
        #pragma unroll
        for (int n = 0; n < 2; ++n) acc[m][n] = (f32x4)0.f;
    float babs = 0.f;
    f32x4 a0[2], a1[2];
    float b0[8], b1[8];

    auto loadS = [&](f32x4* a, float* b, int t) {
        const float* ap = apb + t * 32;
        a[0] = *(const f32x4*)ap;
        a[1] = *(const f32x4*)(ap + (size_t)32 * K);
        const float* bp = bpb + (size_t)t * 32 * N;
        #pragma unroll
        for (int j = 0; j < 8; ++j) b[j] = bp[(size_t)j * N];
    };
    auto writeS = [&](int buf, const f32x4* a, const float* b) {
        #pragma unroll
        for (int i = 0; i < 2; ++i) {
            u32x2 pa = { pkbf(a[i][0], a[i][1]), pkbf(a[i][2], a[i][3]) };
            *(u32x2*)&Al[buf][awr + i * 32 * LDA3] = pa;
        }
        u32x4 pb = { pkbf(b[0], b[1]), pkbf(b[2], b[3]),
                     pkbf(b[4], b[5]), pkbf(b[6], b[7]) };
        *(u32x4*)&Bl[buf][bwr] = pb;
        #pragma unroll
        for (int j = 0; j < 8; ++j) babs += fabsf(b[j]);
    };
    auto mfmaPh = [&](int buf) {
        const int ko = (lane >> 4) * 8;
        bf16x8 af[2], bfr[2];
        #pragma unroll
        for (int m = 0; m < 2; ++m)
            af[m] = *(const bf16x8*)&Al[buf][(wm * 32 + m * 16 + (lane & 15)) * LDA3 + ko];
        #pragma unroll
        for (int n = 0; n < 2; ++n)
            bfr[n] = *(const bf16x8*)&Bl[buf][(wn * 32 + n * 16 + (lane & 15)) * LDB3 + ko];
        #pragma unroll
        for (int m = 0; m < 2; ++m)
            #pragma unroll
            for (int n = 0; n < 2; ++n)
                acc[m][n] = __builtin_amdgcn_mfma_f32_16x16x32_bf16(
                    af[m], bfr[n], acc[m][n], 0, 0, 0);
    };

    loadS(a0, b0, 0);
    writeS(0, a0, b0);
    asm volatile("s_waitcnt lgkmcnt(0)" ::: "memory");
    __builtin_amdgcn_s_barrier();
    loadS(a0, b0, 1);
    loadS(a1, b1, 2);
    for (int t = 0; t < 64; t += 2) {
        mfmaPh(0);
        writeS(1, a0, b0);
        if (t + 3 < 64) loadS(a0, b0, t + 3);
        asm volatile("s_waitcnt lgkmcnt(0)" ::: "memory");
        __builtin_amdgcn_s_barrier();
        mfmaPh(1);
        if (t + 2 < 64) writeS(0, a1, b1);
        if (t + 4 < 64) loadS(a1, b1, t + 4);
        asm volatile("s_waitcnt lgkmcnt(0)" ::: "memory");
        __builtin_amdgcn_s_barrier();
    }
    scr[(tid >> 6) * 64 + bn_] = babs;
    __syncthreads();
    #pragma unroll
    for (int n = 0; n < 2; ++n) {
        const int lc = wn * 32 + n * 16 + (lane & 15);
        const int gc = bcol + lc;
        const float be = 0.1f * (scr[lc] + scr[64 + lc] + scr[128 + lc] + scr[192 + lc]);
        const float ct = cterm[gc];
        #pragma unroll
        for (int m = 0; m < 2; ++m) {
            const int gr0 = brow + wm * 32 + m * 16 + (lane >> 4) * 4;
            f32x4 v = acc[m][n];
            #pragma unroll
            for (int rr = 0; rr < 4; ++rr) {
                size_t idx = (size_t)(gr0 + rr) * N + gc;
                out[idx] = v[rr] + ct - be * y[idx];
            }
        }
    }
}

extern "C" void kernel_launch(void* const* d_in, const int* in_sizes, int n_in,
                              void* d_out, int out_size, void* d_ws, size_t ws_size,
                              hipStream_t stream) {
    const float* x        = (const float*)d_in[0];
    const float* y        = (const float*)d_in[1];
    const float* beta     = (const float*)d_in[2];
    const float* bias_lin = (const float*)d_in[3];
    const float* W2       = (const float*)d_in[5];
    const float* bias2    = (const float*)d_in[7];
    float* out = (float*)d_out;

    const size_t need = 8192 + (size_t)M * K * 2 + (size_t)N * K * 2;  // ~21 MB
    if (ws_size >= need) {
        float* braw = (float*)d_ws;                       // [1024]
        float* wsum = braw + 1024;                        // [1024]
        short* xb   = (short*)((char*)d_ws + 8192);       // [M][K] bf16
        short* bts  = xb + (size_t)M * K;                 // [N][K] bf16 (beta^T)
        hipMemsetAsync(braw, 0, 1024 * sizeof(float), stream);
        pre_kernel<<<1024, 256, 0, stream>>>(x, beta, W2, xb, bts, braw, wsum);
        gemm_kernel<<<512, 256, 0, stream>>>(xb, bts, y, braw, wsum,
                                             bias_lin, bias2, out);
    } else {
        float* cterm = (float*)d_ws;                      // [1024]
        prep3_kernel<<<256, 256, 0, stream>>>(W2, bias_lin, bias2, cterm);
        gemm3_kernel<<<1024, 256, 0, stream>>>(x, beta, y, cterm, out);
    }
}